// Round 4
// baseline (122.011 us; speedup 1.0000x reference)
//
#include <hip/hip_runtime.h>
#include <hip/hip_bf16.h>

#define NUM_BUCKETS 8192
#define ROW_THREADS 256
#define NBLOCKS 1280  // 5 blocks/CU x 256 CUs (LDS-limited residency)

typedef float f32x4 __attribute__((ext_vector_type(4)));

// Kernel 1: exclusive prefix sum of row_lengths -> offs[0..B].
// Single block, 1024 threads, 16 elems/thread, shfl-based (~4 barriers/chunk).
__global__ __launch_bounds__(1024) void scan_rows_kernel(
    const int* __restrict__ row_len, int* __restrict__ offs, int B) {
    __shared__ int wave_sums[16];
    __shared__ int carry_s;
    const int t = threadIdx.x;
    const int wave = t >> 6, lane = t & 63;
    if (t == 0) carry_s = 0;
    __syncthreads();
    const int CHUNK = 1024 * 16;
    for (int base = 0; base < B; base += CHUNK) {
        int v[16];
        const int idx0 = base + t * 16;
        int local = 0;
        #pragma unroll
        for (int e = 0; e < 16; ++e) {
            const int i = idx0 + e;
            const int x = (i < B) ? row_len[i] : 0;
            v[e] = local;          // exclusive within thread
            local += x;
        }
        int incl = local;
        #pragma unroll
        for (int d = 1; d < 64; d <<= 1) {
            const int y = __shfl_up(incl, d, 64);
            if (lane >= d) incl += y;
        }
        if (lane == 63) wave_sums[wave] = incl;
        __syncthreads();
        if (wave == 0) {
            int s = (lane < 16) ? wave_sums[lane] : 0;
            #pragma unroll
            for (int d = 1; d < 16; d <<= 1) {
                const int y = __shfl_up(s, d, 64);
                if (lane >= d) s += y;
            }
            if (lane < 16) wave_sums[lane] = s;
        }
        __syncthreads();
        const int carry = carry_s;
        const int wave_excl = (wave == 0) ? 0 : wave_sums[wave - 1];
        const int texcl = carry + wave_excl + (incl - local);
        #pragma unroll
        for (int e = 0; e < 16; ++e) {
            const int i = idx0 + e;
            if (i < B) offs[i] = texcl + v[e];
        }
        if (t == 0 && base + CHUNK >= B) offs[B] = carry + wave_sums[15];
        __syncthreads();
        if (t == 0) carry_s = carry + wave_sums[15];
        __syncthreads();
    }
}

// Kernel 2: persistent blocks, grid-stride over rows, 1-deep prefetch
// pipeline. Per row: zero LDS, (prefetch next row's ids/weights), barrier,
// LDS atomics, barrier, stream row out with 16B nontemporal stores.
__global__ __launch_bounds__(ROW_THREADS) void nhot_persist_kernel(
    const int* __restrict__ ids, const float* __restrict__ w,
    const int* __restrict__ offs, float* __restrict__ out, int B) {
    __shared__ float lds[NUM_BUCKETS];
    const int t = threadIdx.x;
    const int stride = gridDim.x;
    int r = blockIdx.x;
    if (r >= B) return;

    // prologue: row r metadata + payload
    int s = offs[r], e = offs[r + 1];
    int n = e - s;
    int id = 0; float wt = 0.f;
    if (t < n) { id = ids[s + t]; wt = w[s + t]; }

    f32x4* ldsv = reinterpret_cast<f32x4*>(lds);
    const f32x4 z = {0.f, 0.f, 0.f, 0.f};

    for (;;) {
        // zero the row in LDS (8 x ds_write_b128 per thread)
        #pragma unroll
        for (int k = 0; k < NUM_BUCKETS / 4 / ROW_THREADS; ++k)
            ldsv[k * ROW_THREADS + t] = z;

        // prefetch next row while zero/atomics/stores run
        const int r2 = r + stride;
        int s2 = 0, e2 = 0, n2 = 0, id2 = 0; float wt2 = 0.f;
        if (r2 < B) {
            s2 = offs[r2]; e2 = offs[r2 + 1]; n2 = e2 - s2;
            if (t < n2) { id2 = ids[s2 + t]; wt2 = w[s2 + t]; }
        }

        __syncthreads();  // zero visible to all before atomics
        if (t < n) atomicAdd(&lds[id], wt);
        for (int i = s + t + ROW_THREADS; i < e; i += ROW_THREADS)  // general tail
            atomicAdd(&lds[ids[i]], w[i]);
        __syncthreads();  // atomics done before stores read

        f32x4* outv = reinterpret_cast<f32x4*>(out + (size_t)r * NUM_BUCKETS);
        #pragma unroll
        for (int k = 0; k < NUM_BUCKETS / 4 / ROW_THREADS; ++k)
            __builtin_nontemporal_store(ldsv[k * ROW_THREADS + t],
                                        &outv[k * ROW_THREADS + t]);

        if (r2 >= B) break;
        r = r2; s = s2; e = e2; n = n2; id = id2; wt = wt2;
        // no barrier needed: next zero writes exactly the LDS words this
        // thread just read for its stores; the pre-atomic barrier orders
        // everything else.
    }
}

extern "C" void kernel_launch(void* const* d_in, const int* in_sizes, int n_in,
                              void* d_out, int out_size, void* d_ws, size_t ws_size,
                              hipStream_t stream) {
    const int*   ids     = (const int*)d_in[0];    // values (NNZ,1) int32
    const int*   row_len = (const int*)d_in[1];    // row_lengths (B,1) int32
    const float* wvals   = (const float*)d_in[2];  // weight_values (NNZ,1) f32
    // d_in[3] = weight_row_lengths (unused by reference)

    const int B = in_sizes[1];
    float* out = (float*)d_out;
    int* offs = (int*)d_ws;  // needs (B+1)*4 bytes

    scan_rows_kernel<<<1, 1024, 0, stream>>>(row_len, offs, B);
    const int nblocks = (B < NBLOCKS) ? B : NBLOCKS;
    nhot_persist_kernel<<<nblocks, ROW_THREADS, 0, stream>>>(ids, wvals, offs, out, B);
}